// Round 2
// baseline (448.854 us; speedup 1.0000x reference)
//
#include <hip/hip_runtime.h>
#include <hip/hip_bf16.h>

#define T_ 256
#define B_ 16
#define S_ 64
#define D_ 256

typedef __attribute__((ext_vector_type(4))) int int4v;

// LDS-visibility-only barrier: waits DS ops, leaves global loads/stores/atomics
// in flight across the barrier (avoids the __syncthreads vmcnt(0) drain).
#define LDS_BARRIER() asm volatile("s_waitcnt lgkmcnt(0)\n\ts_barrier" ::: "memory")

// ---------------- W_x transpose: WxT[k][d] = W_x[d][k] ----------------
__global__ void k_transpose(const float* __restrict__ in, float* __restrict__ out) {
    __shared__ float tile[32][33];
    int tx = threadIdx.x & 31, ty = threadIdx.x >> 5;
    int bx = blockIdx.x & 7, by = blockIdx.x >> 3;
    tile[ty][tx] = in[(by * 32 + ty) * D_ + bx * 32 + tx];
    __syncthreads();
    out[(bx * 32 + ty) * D_ + by * 32 + tx] = tile[tx][ty];
}

// ---- wz[t*B+b][d] = { bias[d] + sum_k x[t,b,k]*WxT[k][d],  silu(z[t,b,d]) } ----
__global__ __launch_bounds__(256) void k_wxall(const float* __restrict__ x,
                                               const float* __restrict__ z,
                                               const float* __restrict__ WxT,
                                               const float* __restrict__ bias,
                                               float2* __restrict__ wz) {
    __shared__ float xs[16][D_];
    const int tid = threadIdx.x;
    const int row0 = blockIdx.x * 16;
    for (int r = 0; r < 16; ++r)
        xs[r][tid] = x[(size_t)(row0 + r) * D_ + tid];
    __syncthreads();
    float acc[16];
    float bv = bias[tid];
#pragma unroll
    for (int r = 0; r < 16; ++r) acc[r] = bv;
    for (int k = 0; k < D_; ++k) {
        float wv = WxT[k * D_ + tid];
#pragma unroll
        for (int r = 0; r < 16; ++r) acc[r] = __builtin_fmaf(wv, xs[r][k], acc[r]);
    }
    for (int r = 0; r < 16; ++r) {
        float zv = z[(size_t)(row0 + r) * D_ + tid];
        float sil = zv * __builtin_amdgcn_rcpf(1.0f + __expf(-zv));
        wz[(size_t)(row0 + r) * D_ + tid] = make_float2(acc[r], sil);
    }
}

// ---------------- main recurrence (i8 MFMA K=64) ----------------
// R14: dual-problem software pipeline. One block = 8 slots = TWO independent
// 4-slot problems P0/P1 (slots are independent 256-dim recurrences; the
// all-to-all h exchange is per-slot only). Per iteration, ONE instruction
// stream runs two half-step phases:
//   X: P0 {ds_read A, MFMA x8/wave} overlapped with P1 {epilogue of its
//      previous compute, LDS write} + P0 deferred output;  barrier.
//   Y: mirrored (P1 compute, P0 epilogue);                 barrier.
// Per problem-step the pipe counts are IDENTICAL to the 377.9us baseline
// (16 MFMA/SIMD, 4 ds_read_b128 + 2 b8 writes, 1 barrier, same M-packing of
// 4 slots -> 4x replication; R13's mistake of doubling MFMA is avoided).
// Only the interleave changes: each problem's serial latency segments
// (ds_read ~120cyc, MFMA-result+tanh tail ~140cyc, barrier wait) are filled
// with the OTHER problem's MFMA issue / VALU — compile-time overlap, no
// scheduler reliance (R13 showed co-resident wgs phase-lock and give none).
// Grid = 128 blocks (half the CUs idle — irrelevant: latency-bound).
// Bf (Wh quant, 32 VGPR) and the wz stream are shared (same b).
__global__ __launch_bounds__(512, 1) void k_rec(
    const float* __restrict__ Wh,      // [D][D] (n-major: Wh[n][k])
    const float2* __restrict__ wz,     // [T*B][D] {wx+bias, silu(z)}
    const float* __restrict__ h0,      // [B][S][D]
    const float* __restrict__ Cvec,    // [S]
    float* __restrict__ outputs,       // [T*B][D], pre-zeroed (atomic accum)
    float* __restrict__ h_out)         // [(T+1)*B][S][D]
{
    const int tid  = threadIdx.x;
    const int w    = tid >> 6;               // wave 0..7, owns cols 32w..32w+31
    const int lane = tid & 63;
    const int l16  = lane & 15;
    const int quad = lane >> 4;
    const int b    = blockIdx.x >> 3;
    const int sb8  = (blockIdx.x & 7) * 8;   // P0: sb8..+3, P1: sb8+4..+7
    const int rp   = quad & 2;               // slot-pair this thread finalizes
    const int d    = (w << 5) | (lane & 31); // this thread's output column

    // per-problem ping-pong h buffers, i8. Row stride 288 B (row1 +8 banks):
    // the 16 distinct b128 A-chunks land 2-way per bank (free, m136).
    // Buffer strides (1152/2304 B) are 0 mod 32 banks -> same pattern each.
    __shared__ __align__(16) signed char hA8[2][2][4][288];  // [prob][pp][slot][.]

    // init hA8[*][0] from h0 and write h[0] rows (512 threads, 4 iters)
    for (int i = tid; i < 8 * D_; i += 512) {
        int p = i >> 10, r = (i >> 8) & 3, dd = i & 255;
        float v = h0[(size_t)(b * S_ + sb8 + p * 4 + r) * D_ + dd];
        float vc = fminf(fmaxf(v, -1.0f), 1.0f);
        hA8[p][0][r][dd] = (signed char)__float2int_rn(vc * 127.0f);
        h_out[(size_t)(b * S_ + sb8 + p * 4 + r) * D_ + dd] = v;
    }

    // ---- pass 1: per-column absmax of Wh for cols n = 32w + nt*16 + l16 ----
    float cmax[2];
#pragma unroll
    for (int nt = 0; nt < 2; ++nt) {
        const float* wr = Wh + (size_t)(w * 32 + nt * 16 + l16) * D_ + quad * 16;
        float cm = 1e-20f;
#pragma unroll
        for (int kt = 0; kt < 4; ++kt) {
            const float* p = wr + kt * 64;
#pragma unroll
            for (int j = 0; j < 16; j += 4) {
                float4 v = *(const float4*)(p + j);
                cm = fmaxf(cm, fmaxf(fmaxf(fabsf(v.x), fabsf(v.y)),
                                     fmaxf(fabsf(v.z), fabsf(v.w))));
            }
        }
        cm = fmaxf(cm, __shfl_xor(cm, 16, 64));
        cm = fmaxf(cm, __shfl_xor(cm, 32, 64));
        cmax[nt] = cm;
    }

    // ---- pass 2: quantize Wh -> i8 B-fragments (32 VGPRs), shared by P0/P1 ----
    // lane holds B[k = kt*64 + quad*16 + j][n = 32w + nt*16 + l16]
    int4v Bf[4][2];
#pragma unroll
    for (int nt = 0; nt < 2; ++nt) {
        const float rs = 127.0f / cmax[nt];
        const float* wr = Wh + (size_t)(w * 32 + nt * 16 + l16) * D_ + quad * 16;
#pragma unroll
        for (int kt = 0; kt < 4; ++kt) {
            const float* p = wr + kt * 64;
            int4v frag;
#pragma unroll
            for (int r = 0; r < 4; ++r) {
                float4 v = *(const float4*)(p + r * 4);
                int q0 = __float2int_rn(v.x * rs) & 255;
                int q1 = __float2int_rn(v.y * rs) & 255;
                int q2 = __float2int_rn(v.z * rs) & 255;
                int q3 = __float2int_rn(v.w * rs) & 255;
                frag[r] = q0 | (q1 << 8) | (q2 << 16) | (q3 << 24);
            }
            Bf[kt][nt] = frag;
        }
    }
    // dequant scale folded with the tanh x2: pre2 = 2*(acc*dscale + wx)
    const float dscale2 = ((quad & 1) ? cmax[1] : cmax[0]) * (2.0f / 16129.0f);
    // C coefficients pre-scaled by 1/127 (deferred values are 127*h)
    const float c00 = Cvec[sb8 + rp]         * (1.0f / 127.0f);
    const float c01 = Cvec[sb8 + rp + 1]     * (1.0f / 127.0f);
    const float c10 = Cvec[sb8 + 4 + rp]     * (1.0f / 127.0f);
    const float c11 = Cvec[sb8 + 4 + rp + 1] * (1.0f / 127.0f);

    // prologue: wz for t=0 and t=1; running pointers (shared b => shared stream)
    const float2* wzp = wz + (size_t)b * D_ + d;
    float2 wzr[2];
    wzr[0] = wzp[0];
    wzr[1] = wzp[(size_t)B_ * D_];
    wzp += (size_t)2 * B_ * D_;                 // points at t=2's row

    // per-problem deferred state: f* hold 127*tanh values of the latest h
    float f0P0 = 0.f, f1P0 = 0.f, fsil0 = 0.f, wx20 = 0.f;
    float f0P1 = 0.f, f1P1 = 0.f, fsil1 = 0.f, wx21 = 0.f;
    float* hp0 = h_out + (size_t)(1 * B_ + b) * (S_ * D_) + (size_t)(sb8 + rp) * D_ + d;
    float* hp1 = h_out + (size_t)(1 * B_ + b) * (S_ * D_) + (size_t)(sb8 + 4 + rp) * D_ + d;
    float* op0 = outputs + (size_t)b * D_ + d;
    float* op1 = outputs + (size_t)b * D_ + d;

    // accumulators carried across phases (named regs: no runtime indexing)
    int4v p0_aa, p0_ab, p0_ba, p0_bb;
    int4v p1_aa, p1_ab, p1_ba, p1_bb;

    __syncthreads();   // full barrier once (init visibility incl. global)

// ---- helper macros ----
// EPILOGUE: finish a compute — route accs -> 127*tanh -> i8 LDS write, set f*.
// Slot index == accumulator reg index (C row m = 4*quad+reg, slot = m&3 = reg).
#define EPILOGUE(AA, AB, BA, BB, WX2, F0, F1, PROB, PPW)                       \
    {                                                                          \
        int u0 = (quad & 2) ? AA[2] : AA[0];                                   \
        int u1 = (quad & 2) ? AB[2] : AB[0];                                   \
        int v0 = (quad & 2) ? BA[2] : BA[0];                                   \
        int v1 = (quad & 2) ? BB[2] : BB[0];                                   \
        int sa = (quad & 1) ? (v0 + v1) : (u0 + u1);                           \
        int u2 = (quad & 2) ? AA[3] : AA[1];                                   \
        int u3 = (quad & 2) ? AB[3] : AB[1];                                   \
        int v2 = (quad & 2) ? BA[3] : BA[1];                                   \
        int v3 = (quad & 2) ? BB[3] : BB[1];                                   \
        int sbv = (quad & 1) ? (v2 + v3) : (u2 + u3);                          \
        /* 127*tanh(pre) = 127 - 254/(exp(2*pre)+1) */                         \
        float e0 = __expf(__builtin_fmaf((float)sa, dscale2, WX2));            \
        float e1 = __expf(__builtin_fmaf((float)sbv, dscale2, WX2));           \
        float g0 = __builtin_fmaf(-254.0f, __builtin_amdgcn_rcpf(e0 + 1.0f), 127.0f); \
        float g1 = __builtin_fmaf(-254.0f, __builtin_amdgcn_rcpf(e1 + 1.0f), 127.0f); \
        /* i8 RNE via magic number: low byte of bits(g + 1.5*2^23) */          \
        union { float f; int i; } m0, m1;                                      \
        m0.f = g0 + 12582912.0f;                                               \
        m1.f = g1 + 12582912.0f;                                               \
        hA8[PROB][PPW][rp][d]     = (signed char)m0.i;                         \
        hA8[PROB][PPW][rp + 1][d] = (signed char)m1.i;                         \
        F0 = g0; F1 = g1;                                                      \
    }

// DEFERRED: previous step's output path (h store + C-partial + silu + atomic),
// runs in a ds_read latency shadow; global ops stay in flight across barriers.
#define DEFERRED(F0, F1, FSIL, HP, OP, C0, C1)                                 \
    {                                                                          \
        float hv0 = F0 * (1.0f / 127.0f);                                      \
        float hv1 = F1 * (1.0f / 127.0f);                                      \
        __builtin_nontemporal_store(hv0, HP);                                  \
        __builtin_nontemporal_store(hv1, HP + D_);                             \
        HP += B_ * S_ * D_;                                                    \
        float part = __builtin_fmaf(C0, F0, C1 * F1);                          \
        part += __shfl_xor(part, 32, 64);  /* combine slot-pairs */            \
        if (quad < 2) atomicAdd(OP, part * FSIL);                              \
        OP += B_ * D_;                                                         \
    }

#define MFMA8(AA, AB, BA, BB, F0v, F1v, F2v, F3v)                              \
    {                                                                          \
        int4v zz = {0, 0, 0, 0};                                               \
        AA = zz; AB = zz; BA = zz; BB = zz;                                    \
        AA = __builtin_amdgcn_mfma_i32_16x16x64_i8(F0v, Bf[0][0], AA, 0, 0, 0);\
        BA = __builtin_amdgcn_mfma_i32_16x16x64_i8(F0v, Bf[0][1], BA, 0, 0, 0);\
        AB = __builtin_amdgcn_mfma_i32_16x16x64_i8(F1v, Bf[1][0], AB, 0, 0, 0);\
        BB = __builtin_amdgcn_mfma_i32_16x16x64_i8(F1v, Bf[1][1], BB, 0, 0, 0);\
        AA = __builtin_amdgcn_mfma_i32_16x16x64_i8(F2v, Bf[2][0], AA, 0, 0, 0);\
        BA = __builtin_amdgcn_mfma_i32_16x16x64_i8(F2v, Bf[2][1], BA, 0, 0, 0);\
        AB = __builtin_amdgcn_mfma_i32_16x16x64_i8(F3v, Bf[3][0], AB, 0, 0, 0);\
        BB = __builtin_amdgcn_mfma_i32_16x16x64_i8(F3v, Bf[3][1], BB, 0, 0, 0);\
    }

// One iteration = one t-step of BOTH problems, two phases, two barriers.
// FULL=0 only for t=0 (no previous compute/output). PF: prefetch wz[t+2].
#define ITER(CUR, NXT, FULL, PF)                                               \
    {                                                                          \
        /* ---------- X: P0 compute(t) ; P1 finish(t-1) ---------- */          \
        const signed char* ap0 = &hA8[0][CUR][l16 & 3][quad * 16];             \
        int4v Xf0 = *(const int4v*)(ap0);                                      \
        int4v Xf1 = *(const int4v*)(ap0 + 64);                                 \
        int4v Xf2 = *(const int4v*)(ap0 + 128);                                \
        int4v Xf3 = *(const int4v*)(ap0 + 192);                                \
        if (FULL) {                                                            \
            EPILOGUE(p1_aa, p1_ab, p1_ba, p1_bb, wx21, f0P1, f1P1, 1, CUR)     \
            DEFERRED(f0P0, f1P0, fsil0, hp0, op0, c00, c01)                    \
        }                                                                      \
        wx20  = wzr[CUR].x + wzr[CUR].x;                                       \
        fsil0 = wzr[CUR].y;                                                    \
        MFMA8(p0_aa, p0_ab, p0_ba, p0_bb, Xf0, Xf1, Xf2, Xf3)                  \
        LDS_BARRIER();                                                         \
        /* ---------- Y: P1 compute(t) ; P0 finish(t) ---------- */            \
        const signed char* ap1 = &hA8[1][CUR][l16 & 3][quad * 16];             \
        int4v Yf0 = *(const int4v*)(ap1);                                      \
        int4v Yf1 = *(const int4v*)(ap1 + 64);                                 \
        int4v Yf2 = *(const int4v*)(ap1 + 128);                                \
        int4v Yf3 = *(const int4v*)(ap1 + 192);                                \
        if (FULL) {                                                            \
            DEFERRED(f0P1, f1P1, fsil1, hp1, op1, c10, c11)                    \
        }                                                                      \
        EPILOGUE(p0_aa, p0_ab, p0_ba, p0_bb, wx20, f0P0, f1P0, 0, NXT)         \
        wx21  = wzr[CUR].x + wzr[CUR].x;                                       \
        fsil1 = wzr[CUR].y;                                                    \
        if (PF) { wzr[CUR] = *wzp; wzp += (size_t)B_ * D_; }                   \
        MFMA8(p1_aa, p1_ab, p1_ba, p1_bb, Yf0, Yf1, Yf2, Yf3)                  \
        LDS_BARRIER();                                                         \
    }

    ITER(0, 1, 0, 1)                                   // t = 0
    for (int t2 = 1; t2 < 253; t2 += 2) {              // t = 1..252
        ITER(1, 0, 1, 1)
        ITER(0, 1, 1, 1)
    }
    ITER(1, 0, 1, 1)                                   // t = 253 (PF -> wz[255])
    ITER(0, 1, 1, 0)                                   // t = 254
    ITER(1, 0, 1, 0)                                   // t = 255
#undef ITER
#undef MFMA8

    // tail: P1's last epilogue + both problems' final output flush
    {
        DEFERRED(f0P0, f1P0, fsil0, hp0, op0, c00, c01)    // h_P0(256), out[255]
        EPILOGUE(p1_aa, p1_ab, p1_ba, p1_bb, wx21, f0P1, f1P1, 1, 0)
        DEFERRED(f0P1, f1P1, fsil1, hp1, op1, c10, c11)    // h_P1(256), out[255]
    }
#undef EPILOGUE
#undef DEFERRED
}

extern "C" void kernel_launch(void* const* d_in, const int* in_sizes, int n_in,
                              void* d_out, int out_size, void* d_ws, size_t ws_size,
                              hipStream_t stream) {
    const float* x    = (const float*)d_in[0];
    const float* z    = (const float*)d_in[1];
    const float* h0   = (const float*)d_in[2];
    const float* W_x  = (const float*)d_in[3];
    const float* W_h  = (const float*)d_in[4];
    const float* bias = (const float*)d_in[5];
    const float* C    = (const float*)d_in[6];

    float* outputs = (float*)d_out;                     // [T*B*D]
    float* h_out   = outputs + (size_t)T_ * B_ * D_;    // [(T+1)*B*S*D]

    float*  WxT = (float*)d_ws;                         // D*D floats
    float2* wz  = (float2*)(WxT + D_ * D_);             // T*B*D float2

    hipMemsetAsync(outputs, 0, (size_t)T_ * B_ * D_ * sizeof(float), stream);
    k_transpose<<<64, 1024, 0, stream>>>(W_x, WxT);
    k_wxall<<<T_ * B_ / 16, 256, 0, stream>>>(x, z, WxT, bias, wz);
    k_rec<<<B_ * S_ / 8, 512, 0, stream>>>(W_h, wz, h0, C, outputs, h_out);
}

// Round 3
// 384.618 us; speedup vs baseline: 1.1670x; 1.1670x over previous
//
#include <hip/hip_runtime.h>
#include <hip/hip_bf16.h>

#define T_ 256
#define B_ 16
#define S_ 64
#define D_ 256

typedef __attribute__((ext_vector_type(4))) int int4v;

// LDS-visibility-only barrier: waits DS ops, leaves global loads/stores/atomics
// in flight across the barrier (avoids the __syncthreads vmcnt(0) drain).
#define LDS_BARRIER() asm volatile("s_waitcnt lgkmcnt(0)\n\ts_barrier" ::: "memory")

// ---------------- W_x transpose: WxT[k][d] = W_x[d][k] ----------------
__global__ void k_transpose(const float* __restrict__ in, float* __restrict__ out) {
    __shared__ float tile[32][33];
    int tx = threadIdx.x & 31, ty = threadIdx.x >> 5;
    int bx = blockIdx.x & 7, by = blockIdx.x >> 3;
    tile[ty][tx] = in[(by * 32 + ty) * D_ + bx * 32 + tx];
    __syncthreads();
    out[(bx * 32 + ty) * D_ + by * 32 + tx] = tile[tx][ty];
}

// ---- wz[t*B+b][d] = { bias[d] + sum_k x[t,b,k]*WxT[k][d],  silu(z[t,b,d]) } ----
__global__ __launch_bounds__(256) void k_wxall(const float* __restrict__ x,
                                               const float* __restrict__ z,
                                               const float* __restrict__ WxT,
                                               const float* __restrict__ bias,
                                               float2* __restrict__ wz) {
    __shared__ float xs[16][D_];
    const int tid = threadIdx.x;
    const int row0 = blockIdx.x * 16;
    for (int r = 0; r < 16; ++r)
        xs[r][tid] = x[(size_t)(row0 + r) * D_ + tid];
    __syncthreads();
    float acc[16];
    float bv = bias[tid];
#pragma unroll
    for (int r = 0; r < 16; ++r) acc[r] = bv;
    for (int k = 0; k < D_; ++k) {
        float wv = WxT[k * D_ + tid];
#pragma unroll
        for (int r = 0; r < 16; ++r) acc[r] = __builtin_fmaf(wv, xs[r][k], acc[r]);
    }
    for (int r = 0; r < 16; ++r) {
        float zv = z[(size_t)(row0 + r) * D_ + tid];
        float sil = zv * __builtin_amdgcn_rcpf(1.0f + __expf(-zv));
        wz[(size_t)(row0 + r) * D_ + tid] = make_float2(acc[r], sil);
    }
}

// ---------------- main recurrence (i8 MFMA K=64) ----------------
// R15: 4-wave / wide-N topology. Same 256 blocks x 1 problem (4 slots) as the
// 377.9us baseline, but 256 threads (4 waves, 1/SIMD), each wave owning N=64
// (4 B-chains nt=0..3 x kt=0..3 = 16 MFMA/wave, 4-deep kt accumulation).
// Per-SIMD per step this keeps MFMA issue identical to baseline (16 instr,
// ~326cyc) and epilogue VALU identical (1 wave x 4 tanh vs 2 x 2), but HALVES
// the DS-pipe instruction count (16 ds_read_b128 + 16 ds_write_b8 vs 32+16,
// ~480->~290cyc serialized) — the largest term in the 1210-cyc step wall.
// R14 measured ~590cyc of that wall to be fillable stall; DS-pipe is the
// prime suspect. Structural bonuses of 4 chains/thread: quad q's C-regs
// 0..3 are slots 0..3 of col d = w*64 + quad*16 + l16, so each thread owns
// one full output column -> no shfl_xor combine, no divergent atomic mask,
// no chain-pair integer adds. Barrier population halves (4 waves).
__global__ __launch_bounds__(256, 1) void k_rec(
    const float* __restrict__ Wh,      // [D][D] (n-major: Wh[n][k])
    const float2* __restrict__ wz,     // [T*B][D] {wx+bias, silu(z)}
    const float* __restrict__ h0,      // [B][S][D]
    const float* __restrict__ Cvec,    // [S]
    float* __restrict__ outputs,       // [T*B][D], pre-zeroed (atomic accum)
    float* __restrict__ h_out)         // [(T+1)*B][S][D]
{
    const int tid  = threadIdx.x;              // 0..255
    const int w    = tid >> 6;                 // wave 0..3, owns cols 64w..64w+63
    const int lane = tid & 63;
    const int l16  = lane & 15;
    const int quad = lane >> 4;
    const int b    = blockIdx.x >> 4;
    const int s0   = (blockIdx.x & 15) * 4;
    const int d    = (w << 6) | (quad << 4) | l16;   // owned output column

    // ping-pong h buffer, i8. Row stride 288 B: the 16 distinct b128 A-chunks
    // land 2-way per bank (free, m136); b8 writes same pattern as baseline
    // (0 conflicts measured R3-R14).
    __shared__ __align__(16) signed char hA8[2][4][288];

    // init hA8[0] from h0 and write h[0] = h0  (256 threads, 4 iters)
    for (int i = tid; i < 4 * D_; i += 256) {
        int r = i >> 8, dd = i & 255;
        float v = h0[(size_t)(b * S_ + s0 + r) * D_ + dd];
        float vc = fminf(fmaxf(v, -1.0f), 1.0f);
        hA8[0][r][dd] = (signed char)__float2int_rn(vc * 127.0f);
        h_out[(size_t)(b * S_ + s0 + r) * D_ + dd] = v;
    }

    // ---- pass 1: per-column absmax of Wh for cols n = 64w + nt*16 + l16 ----
    float cmax[4];
#pragma unroll
    for (int nt = 0; nt < 4; ++nt) {
        const float* wr = Wh + (size_t)(w * 64 + nt * 16 + l16) * D_ + quad * 16;
        float cm = 1e-20f;
#pragma unroll
        for (int kt = 0; kt < 4; ++kt) {
            const float* p = wr + kt * 64;
#pragma unroll
            for (int j = 0; j < 16; j += 4) {
                float4 v = *(const float4*)(p + j);
                cm = fmaxf(cm, fmaxf(fmaxf(fabsf(v.x), fabsf(v.y)),
                                     fmaxf(fabsf(v.z), fabsf(v.w))));
            }
        }
        cm = fmaxf(cm, __shfl_xor(cm, 16, 64));
        cm = fmaxf(cm, __shfl_xor(cm, 32, 64));
        cmax[nt] = cm;
    }

    // ---- pass 2: quantize Wh -> i8 B-fragments (64 VGPRs) ----
    // lane holds B[k = kt*64 + quad*16 + j][n = 64w + nt*16 + l16]
    int4v Bf[4][4];   // [kt][nt]
#pragma unroll
    for (int nt = 0; nt < 4; ++nt) {
        const float rs = 127.0f / cmax[nt];
        const float* wr = Wh + (size_t)(w * 64 + nt * 16 + l16) * D_ + quad * 16;
#pragma unroll
        for (int kt = 0; kt < 4; ++kt) {
            const float* p = wr + kt * 64;
            int4v frag;
#pragma unroll
            for (int r = 0; r < 4; ++r) {
                float4 v = *(const float4*)(p + r * 4);
                int q0 = __float2int_rn(v.x * rs) & 255;
                int q1 = __float2int_rn(v.y * rs) & 255;
                int q2 = __float2int_rn(v.z * rs) & 255;
                int q3 = __float2int_rn(v.w * rs) & 255;
                frag[r] = q0 | (q1 << 8) | (q2 << 16) | (q3 << 24);
            }
            Bf[kt][nt] = frag;
        }
    }
    // dequant scale for the owned column d (chain nt == quad), folded with the
    // tanh x2: pre2 = 2*(acc*dscale + wx). Constant-index selects only.
    const float dsA     = (quad & 1) ? cmax[1] : cmax[0];
    const float dsB     = (quad & 1) ? cmax[3] : cmax[2];
    const float dscale2 = ((quad & 2) ? dsB : dsA) * (2.0f / 16129.0f);
    // C coefficients pre-scaled by 1/127 (deferred values are 127*h)
    const float c0i = Cvec[s0]     * (1.0f / 127.0f);
    const float c1i = Cvec[s0 + 1] * (1.0f / 127.0f);
    const float c2i = Cvec[s0 + 2] * (1.0f / 127.0f);
    const float c3i = Cvec[s0 + 3] * (1.0f / 127.0f);

    // prologue: wz for t=0 and t=1; running pointers
    const float2* wzp = wz + (size_t)b * D_ + d;
    float2 wzr[2];
    wzr[0] = wzp[0];
    wzr[1] = wzp[(size_t)B_ * D_];
    wzp += (size_t)2 * B_ * D_;                 // points at t=2's row

    // deferred output state of step t-1: f0..f3 hold 127*tanh of col d, slots 0..3
    float f0 = 0.f, f1 = 0.f, f2 = 0.f, f3 = 0.f, fsil = 0.f;
    float* hp = h_out + (size_t)(1 * B_ + b) * (S_ * D_) + (size_t)s0 * D_ + d;
    float* op = outputs + (size_t)b * D_ + d;

    __syncthreads();   // full barrier once (init visibility incl. global)

// PF = 1: prefetch wz for t+2 (main body); PF = 0: last two steps, no prefetch.
#define STEP(t, CUR, NXT, PF)                                                  \
    {                                                                          \
        const signed char* ap = &hA8[CUR][l16 & 3][quad * 16];                 \
        int4v Af0 = *(const int4v*)(ap);                                       \
        int4v Af1 = *(const int4v*)(ap + 64);                                  \
        int4v Af2 = *(const int4v*)(ap + 128);                                 \
        int4v Af3 = *(const int4v*)(ap + 192);                                 \
        if ((t) >= 1) { /* step t-1's output path, in the ds_read shadow */    \
            float hv0 = f0 * (1.0f / 127.0f);                                  \
            float hv1 = f1 * (1.0f / 127.0f);                                  \
            float hv2 = f2 * (1.0f / 127.0f);                                  \
            float hv3 = f3 * (1.0f / 127.0f);                                  \
            __builtin_nontemporal_store(hv0, hp);                              \
            __builtin_nontemporal_store(hv1, hp + D_);                         \
            __builtin_nontemporal_store(hv2, hp + 2 * D_);                     \
            __builtin_nontemporal_store(hv3, hp + 3 * D_);                     \
            hp += B_ * S_ * D_;                                                \
            float part = __builtin_fmaf(c0i, f0, c1i * f1);                    \
            part = __builtin_fmaf(c2i, f2, part);                              \
            part = __builtin_fmaf(c3i, f3, part);                              \
            atomicAdd(op, part * fsil);                                        \
            op += B_ * D_;                                                     \
        }                                                                      \
        float wx2 = wzr[CUR].x + wzr[CUR].x;                                   \
        fsil      = wzr[CUR].y;                                                \
        if (PF) { wzr[CUR] = *wzp; wzp += (size_t)B_ * D_; }                   \
        /* 4 independent 4-deep MFMA chains; dep pairs 4 instrs apart */       \
        int4v zz = {0, 0, 0, 0};                                               \
        int4v q0 = zz, q1 = zz, q2 = zz, q3 = zz;                              \
        q0 = __builtin_amdgcn_mfma_i32_16x16x64_i8(Af0, Bf[0][0], q0, 0, 0, 0);\
        q1 = __builtin_amdgcn_mfma_i32_16x16x64_i8(Af0, Bf[0][1], q1, 0, 0, 0);\
        q2 = __builtin_amdgcn_mfma_i32_16x16x64_i8(Af0, Bf[0][2], q2, 0, 0, 0);\
        q3 = __builtin_amdgcn_mfma_i32_16x16x64_i8(Af0, Bf[0][3], q3, 0, 0, 0);\
        q0 = __builtin_amdgcn_mfma_i32_16x16x64_i8(Af1, Bf[1][0], q0, 0, 0, 0);\
        q1 = __builtin_amdgcn_mfma_i32_16x16x64_i8(Af1, Bf[1][1], q1, 0, 0, 0);\
        q2 = __builtin_amdgcn_mfma_i32_16x16x64_i8(Af1, Bf[1][2], q2, 0, 0, 0);\
        q3 = __builtin_amdgcn_mfma_i32_16x16x64_i8(Af1, Bf[1][3], q3, 0, 0, 0);\
        q0 = __builtin_amdgcn_mfma_i32_16x16x64_i8(Af2, Bf[2][0], q0, 0, 0, 0);\
        q1 = __builtin_amdgcn_mfma_i32_16x16x64_i8(Af2, Bf[2][1], q1, 0, 0, 0);\
        q2 = __builtin_amdgcn_mfma_i32_16x16x64_i8(Af2, Bf[2][2], q2, 0, 0, 0);\
        q3 = __builtin_amdgcn_mfma_i32_16x16x64_i8(Af2, Bf[2][3], q3, 0, 0, 0);\
        q0 = __builtin_amdgcn_mfma_i32_16x16x64_i8(Af3, Bf[3][0], q0, 0, 0, 0);\
        q1 = __builtin_amdgcn_mfma_i32_16x16x64_i8(Af3, Bf[3][1], q1, 0, 0, 0);\
        q2 = __builtin_amdgcn_mfma_i32_16x16x64_i8(Af3, Bf[3][2], q2, 0, 0, 0);\
        q3 = __builtin_amdgcn_mfma_i32_16x16x64_i8(Af3, Bf[3][3], q3, 0, 0, 0);\
        /* own-column routing: chain index == quad (constant-index selects), */\
        /* regs 0..3 == slots 0..3 of col d */                                 \
        int v0 = (quad & 2) ? ((quad & 1) ? q3[0] : q2[0])                     \
                            : ((quad & 1) ? q1[0] : q0[0]);                    \
        int v1 = (quad & 2) ? ((quad & 1) ? q3[1] : q2[1])                     \
                            : ((quad & 1) ? q1[1] : q0[1]);                    \
        int v2 = (quad & 2) ? ((quad & 1) ? q3[2] : q2[2])                     \
                            : ((quad & 1) ? q1[2] : q0[2]);                    \
        int v3 = (quad & 2) ? ((quad & 1) ? q3[3] : q2[3])                     \
                            : ((quad & 1) ? q1[3] : q0[3]);                    \
        /* 127*tanh(pre) = 127 - 254/(exp(2*pre)+1); minimal chain to LDS */   \
        float e0 = __expf(__builtin_fmaf((float)v0, dscale2, wx2));            \
        float e1 = __expf(__builtin_fmaf((float)v1, dscale2, wx2));            \
        float e2 = __expf(__builtin_fmaf((float)v2, dscale2, wx2));            \
        float e3 = __expf(__builtin_fmaf((float)v3, dscale2, wx2));            \
        float g0 = __builtin_fmaf(-254.0f, __builtin_amdgcn_rcpf(e0 + 1.0f), 127.0f); \
        float g1 = __builtin_fmaf(-254.0f, __builtin_amdgcn_rcpf(e1 + 1.0f), 127.0f); \
        float g2 = __builtin_fmaf(-254.0f, __builtin_amdgcn_rcpf(e2 + 1.0f), 127.0f); \
        float g3 = __builtin_fmaf(-254.0f, __builtin_amdgcn_rcpf(e3 + 1.0f), 127.0f); \
        /* i8 RNE via magic number: low byte of bits(g + 1.5*2^23) */          \
        union { float f; int i; } m0, m1, m2, m3;                              \
        m0.f = g0 + 12582912.0f;                                               \
        m1.f = g1 + 12582912.0f;                                               \
        m2.f = g2 + 12582912.0f;                                               \
        m3.f = g3 + 12582912.0f;                                               \
        hA8[NXT][0][d] = (signed char)m0.i;                                    \
        hA8[NXT][1][d] = (signed char)m1.i;                                    \
        hA8[NXT][2][d] = (signed char)m2.i;                                    \
        hA8[NXT][3][d] = (signed char)m3.i;                                    \
        f0 = g0; f1 = g1; f2 = g2; f3 = g3;                                    \
        LDS_BARRIER();                                                         \
    }

    for (int t2 = 0; t2 < T_ - 2; t2 += 2) {
        STEP(t2, 0, 1, 1)
        STEP(t2 + 1, 1, 0, 1)
    }
    STEP(T_ - 2, 0, 1, 0)
    STEP(T_ - 1, 1, 0, 0)
#undef STEP

    // tail: flush step T-1's output path
    {
        float hv0 = f0 * (1.0f / 127.0f);
        float hv1 = f1 * (1.0f / 127.0f);
        float hv2 = f2 * (1.0f / 127.0f);
        float hv3 = f3 * (1.0f / 127.0f);
        __builtin_nontemporal_store(hv0, hp);
        __builtin_nontemporal_store(hv1, hp + D_);
        __builtin_nontemporal_store(hv2, hp + 2 * D_);
        __builtin_nontemporal_store(hv3, hp + 3 * D_);
        float part = __builtin_fmaf(c0i, f0, c1i * f1);
        part = __builtin_fmaf(c2i, f2, part);
        part = __builtin_fmaf(c3i, f3, part);
        atomicAdd(op, part * fsil);
    }
}

extern "C" void kernel_launch(void* const* d_in, const int* in_sizes, int n_in,
                              void* d_out, int out_size, void* d_ws, size_t ws_size,
                              hipStream_t stream) {
    const float* x    = (const float*)d_in[0];
    const float* z    = (const float*)d_in[1];
    const float* h0   = (const float*)d_in[2];
    const float* W_x  = (const float*)d_in[3];
    const float* W_h  = (const float*)d_in[4];
    const float* bias = (const float*)d_in[5];
    const float* C    = (const float*)d_in[6];

    float* outputs = (float*)d_out;                     // [T*B*D]
    float* h_out   = outputs + (size_t)T_ * B_ * D_;    // [(T+1)*B*S*D]

    float*  WxT = (float*)d_ws;                         // D*D floats
    float2* wz  = (float2*)(WxT + D_ * D_);             // T*B*D float2

    hipMemsetAsync(outputs, 0, (size_t)T_ * B_ * D_ * sizeof(float), stream);
    k_transpose<<<64, 1024, 0, stream>>>(W_x, WxT);
    k_wxall<<<T_ * B_ / 16, 256, 0, stream>>>(x, z, WxT, bias, wz);
    k_rec<<<B_ * S_ / 4, 256, 0, stream>>>(W_h, wz, h0, C, outputs, h_out);
}